// Round 19
// baseline (210.240 us; speedup 1.0000x reference)
//
#include <hip/hip_runtime.h>

#define SCALE 0.125f

constexpr int L_ = 1024, T_ = 1024, D_ = 64, HB_ = 64;

using f32x4 = __attribute__((ext_vector_type(4))) float;
using half8 = __attribute__((ext_vector_type(8))) _Float16;
using half4 = __attribute__((ext_vector_type(4))) _Float16;

// ===========================================================================
// Prologue: V f32 [hb][t][d] -> Vh f16 transposed [hb][d][t]. (r10-proven)
// ===========================================================================
__global__ __launch_bounds__(256) void cvt_v(const float* __restrict__ v,
                                             _Float16* __restrict__ vh) {
  __shared__ _Float16 ts[64][136];
  const int tid = threadIdx.x;
  const int hb = blockIdx.y;
  const int t0 = blockIdx.x * 128;
  {
    const int tr = tid >> 1, dh = (tid & 1) * 32;
    const float* p = v + ((size_t)hb * T_ + t0 + tr) * D_ + dh;
#pragma unroll
    for (int i = 0; i < 8; ++i) {
      f32x4 r = *(const f32x4*)(p + i * 4);
#pragma unroll
      for (int e = 0; e < 4; ++e) ts[dh + i * 4 + e][tr] = (_Float16)r[e];
    }
  }
  __syncthreads();
  {
    const int d = tid >> 2, tq = (tid & 3) * 32;
    _Float16* qo = vh + ((size_t)hb * D_ + d) * T_ + t0 + tq;
#pragma unroll
    for (int i = 0; i < 4; ++i)
      *(half8*)(qo + i * 8) = *(const half8*)&ts[d][tq + i * 8];
  }
}

// ===========================================================================
// Fused kernel (r18 + per-wave chunk-order rotation): 512 threads (8 waves),
// 128 q-rows/block, grid 8x64. Full per-hb K in LDS (143 KB). Per-wave f16
// remap tile Pl[16][64] (XOR-swizzled) for coalesced prev/att streams.
// NEW: each (wave,block) walks chunks in rotated order cc=(i+rot)&15 so the
// concurrent HBM address stream covers ALL 16 column-offsets (4KB-stride
// channel-conflict fix). Z / PV / att are chunk-order independent.
// ===========================================================================
__global__ __launch_bounds__(512) void attn_all(
    const float* __restrict__ q, const float* __restrict__ kk,
    const _Float16* __restrict__ Vh, const float* __restrict__ prev,
    float* __restrict__ out, float* __restrict__ att) {
  __shared__ __align__(16) _Float16 Ks[1024][70];   // 143,360 B full-T K
  __shared__ __align__(16) _Float16 Pl[8][16][64];  // 16,384 B remap tiles

  const int ltile = blockIdx.x;   // 0..7
  const int hb    = blockIdx.y;   // 0..63
  const int tid = threadIdx.x;
  const int w = tid >> 6, l = tid & 63, l15 = l & 15, lg = l >> 4;
  const int qrow = ltile * 128 + w * 16 + l15;

  // chunk-order rotation: spread concurrent col-offsets across waves/blocks
  const int rot = (w + ltile + hb) & 15;
  auto chk = [&](int i) { return (i + rot) & 15; };

  // XOR-swizzled byte accessor for this wave's remap tile
  auto plb = [&](int row, int byte) -> _Float16* {
    return (_Float16*)((unsigned char*)&Pl[w][0][0] + row * 128 +
                       ((unsigned)byte ^ (((unsigned)row & 7) << 4)));
  };

  // ---- stage ALL of K (f32 -> f16): 8 reps x (512 thr x 16 floats)
  {
    const int srow = tid >> 2, scol = (tid & 3) * 16;
    const float* kp0 = kk + (size_t)hb * T_ * D_;
#pragma unroll
    for (int rep = 0; rep < 8; ++rep) {
      const int r = rep * 128 + srow;
      const float* p = kp0 + (size_t)r * D_ + scol;
      f32x4 a = *(const f32x4*)(p);
      f32x4 b = *(const f32x4*)(p + 4);
      f32x4 cc = *(const f32x4*)(p + 8);
      f32x4 d = *(const f32x4*)(p + 12);
      half8 h0, h1;
#pragma unroll
      for (int e = 0; e < 4; ++e) {
        h0[e] = (_Float16)a[e];  h0[4 + e] = (_Float16)b[e];
        h1[e] = (_Float16)cc[e]; h1[4 + e] = (_Float16)d[e];
      }
      *(half8*)&Ks[r][scol] = h0;
      *(half8*)&Ks[r][scol + 8] = h1;
    }
  }

  // Q B-frag (swapped QK^T): lane holds Q[qrow][f*32 + lg*8 + e]
  half8 qb2[2];
  {
    const float* qp = q + ((size_t)hb * L_ + qrow) * D_ + lg * 8;
#pragma unroll
    for (int f = 0; f < 2; ++f)
#pragma unroll
      for (int e = 0; e < 8; ++e) qb2[f][e] = (_Float16)qp[f * 32 + e];
  }

  // coalesced prev pattern: lane -> row (l>>4)+4i, cols (l&15)*4
  const float* prowb =
      prev + ((size_t)hb * L_ + ltile * 128 + w * 16) * (size_t)T_;
  const int cr = l >> 4, cc4 = (l & 15) * 4;

  f32x4 pr[2][4];
  auto pload = [&](int c, int s) {   // c = rotated chunk index
#pragma unroll
    for (int i = 0; i < 4; ++i)
      pr[s][i] =
          *(const f32x4*)(prowb + (size_t)(cr + 4 * i) * T_ + c * 64 + cc4);
  };
  auto pstage = [&](int s) {   // regs -> f16 tile (consume point of pr[s])
#pragma unroll
    for (int i = 0; i < 4; ++i) {
      half4 h;
      h[0] = (_Float16)pr[s][i][0]; h[1] = (_Float16)pr[s][i][1];
      h[2] = (_Float16)pr[s][i][2]; h[3] = (_Float16)pr[s][i][3];
      *(half4*)plb(cr + 4 * i, cc4 * 2) = h;
    }
  };

  __syncthreads();   // K staged; no further block barriers

  // ======================= Phase 1: Z only ================================
  pload(chk(0), 0);
  pload(chk(1), 1);
  float zsum = 0.f;

#pragma unroll 2
  for (int i = 0; i < 16; ++i) {
    const int cbase = chk(i) * 64;
    pstage(i & 1);
    if (i < 14) pload(chk(i + 2), i & 1);

#pragma unroll
    for (int nt = 0; nt < 4; ++nt) {
      const int trow = cbase + nt * 16 + l15;
      half8 ka0 = *(const half8*)&Ks[trow][lg * 8];
      half8 ka1 = *(const half8*)&Ks[trow][32 + lg * 8];
      f32x4 acc = {0.f, 0.f, 0.f, 0.f};
      acc = __builtin_amdgcn_mfma_f32_16x16x32_f16(ka0, qb2[0], acc, 0, 0, 0);
      acc = __builtin_amdgcn_mfma_f32_16x16x32_f16(ka1, qb2[1], acc, 0, 0, 0);

      half4 hv = *(const half4*)plb(l15, (nt * 16 + lg * 4) * 2);
      zsum += __expf(acc[0] * SCALE + (float)hv[0]);
      zsum += __expf(acc[1] * SCALE + (float)hv[1]);
      zsum += __expf(acc[2] * SCALE + (float)hv[2]);
      zsum += __expf(acc[3] * SCALE + (float)hv[3]);
    }
  }

  zsum += __shfl_xor(zsum, 16, 64);
  zsum += __shfl_xor(zsum, 32, 64);
  const float rzq = 1.0f / zsum;

  // ======================= Phase 2: att + PV ==============================
  const _Float16* vbh = Vh + (size_t)hb * D_ * T_;  // [d][t] f16
  float* attb = att + ((size_t)hb * L_ + ltile * 128 + w * 16) * (size_t)T_;

  half8 vr[2][8];
  auto vload = [&](int c, int s) {   // c = rotated chunk index
#pragma unroll
    for (int ks = 0; ks < 2; ++ks)
#pragma unroll
      for (int nd = 0; nd < 4; ++nd)
        vr[s][ks * 4 + nd] =
            *(const half8*)(vbh + (size_t)(nd * 16 + l15) * T_ + c * 64 +
                            ks * 32 + lg * 8);
  };

  pload(chk(0), 0);   // L3-hot re-read
  pload(chk(1), 1);
  vload(chk(0), 0);
  vload(chk(1), 1);

  f32x4 oacc[4];
#pragma unroll
  for (int nd = 0; nd < 4; ++nd) oacc[nd] = (f32x4){0.f, 0.f, 0.f, 0.f};

#pragma unroll 2
  for (int i = 0; i < 16; ++i) {
    const int cbase = chk(i) * 64;
    pstage(i & 1);
    if (i < 14) pload(chk(i + 2), i & 1);

    // recompute scores, normalize, write s back into the tile (same slots)
#pragma unroll
    for (int nt = 0; nt < 4; ++nt) {
      const int trow = cbase + nt * 16 + l15;
      half8 ka0 = *(const half8*)&Ks[trow][lg * 8];
      half8 ka1 = *(const half8*)&Ks[trow][32 + lg * 8];
      f32x4 acc = {0.f, 0.f, 0.f, 0.f};
      acc = __builtin_amdgcn_mfma_f32_16x16x32_f16(ka0, qb2[0], acc, 0, 0, 0);
      acc = __builtin_amdgcn_mfma_f32_16x16x32_f16(ka1, qb2[1], acc, 0, 0, 0);

      half4 hv = *(const half4*)plb(l15, (nt * 16 + lg * 4) * 2);
      float s0 = __expf(acc[0] * SCALE + (float)hv[0]) * rzq;
      float s1 = __expf(acc[1] * SCALE + (float)hv[1]) * rzq;
      float s2 = __expf(acc[2] * SCALE + (float)hv[2]) * rzq;
      float s3 = __expf(acc[3] * SCALE + (float)hv[3]) * rzq;
      half4 sv;
      sv[0] = (_Float16)s0; sv[1] = (_Float16)s1;
      sv[2] = (_Float16)s2; sv[3] = (_Float16)s3;
      *(half4*)plb(l15, (nt * 16 + lg * 4) * 2) = sv;
    }

    // PV: A-frag b128 straight from the tile (f16 s values), B = vr
#pragma unroll
    for (int ks = 0; ks < 2; ++ks) {
      half8 af = *(const half8*)plb(l15, (ks * 32 + lg * 8) * 2);
#pragma unroll
      for (int nd = 0; nd < 4; ++nd)
        oacc[nd] = __builtin_amdgcn_mfma_f32_16x16x32_f16(
            af, vr[i & 1][ks * 4 + nd], oacc[nd], 0, 0, 0);
    }

    // att store-out: 4 instrs, each 4 rows x 256B dense full lines
#pragma unroll
    for (int j = 0; j < 4; ++j) {
      half4 hv = *(const half4*)plb(cr + 4 * j, cc4 * 2);
      f32x4 sv = {(float)hv[0], (float)hv[1], (float)hv[2], (float)hv[3]};
      *(f32x4*)(attb + (size_t)(cr + 4 * j) * T_ + cbase + cc4) = sv;
    }

    if (i < 14) vload(chk(i + 2), i & 1);   // issue V last (youngest)
  }

  // epilogue: oacc[nd][i] = O[q = w*16 + lg*4 + i][d = nd*16 + l15]
  float* outw =
      out + ((size_t)hb * L_ + ltile * 128 + w * 16 + lg * 4) * (size_t)D_;
#pragma unroll
  for (int nd = 0; nd < 4; ++nd)
#pragma unroll
    for (int i = 0; i < 4; ++i)
      outw[(size_t)i * D_ + nd * 16 + l15] = oacc[nd][i];
}

extern "C" void kernel_launch(void* const* d_in, const int* in_sizes, int n_in,
                              void* d_out, int out_size, void* d_ws,
                              size_t ws_size, hipStream_t stream) {
  const float* q    = (const float*)d_in[0];  // (H,B,L,D)
  const float* k    = (const float*)d_in[1];  // (H,B,T,D)
  const float* v    = (const float*)d_in[2];  // (H,B,T,D)
  const float* prev = (const float*)d_in[3];  // (H,B,L,T)

  float* out = (float*)d_out;                 // (H,B,L,D)
  float* att = out + (size_t)HB_ * L_ * D_;   // (H,B,L,T)

  _Float16* Vh = (_Float16*)d_ws;             // 8 MB (ws >= 16 MB proven)

  cvt_v<<<dim3(T_ / 128, HB_), 256, 0, stream>>>(v, Vh);
  attn_all<<<dim3(L_ / 128, HB_), 512, 0, stream>>>(q, k, Vh, prev, out, att);
}